// Round 6
// baseline (241.270 us; speedup 1.0000x reference)
//
#include <hip/hip_runtime.h>
#include <math.h>

// Focal_loss2 — single fused dispatch, barrier-free stencil, hoisted-load version.
//   neg: w = sigmoid(x)^2 * (gt==-1) * (x is 3x3x3 local max); loss += softplus(x)*w
//        local-max test in logit space (monotone sigmoid; validated R3/R4, absmax 0.0)
//   pos: 64 coords/batch/level gather; w1=(1-sigmoid)^2; per-(b,tag) min of w1
// ws (floats): [0]=lossneg_a [1]=wneg_a [2]=lossneg_b [3]=wneg_b
//              [4]=losspos_a [5]=cntpos_a [6]=losspos_b [7]=cntpos_b [8]=block counter
// out: [0]=cls_loss_pos [1]=cls_loss_neg [2]=count_pos [3]=count_neg
//      [4]=wsum_pos [5]=wsum_neg [6..37]=pred_prob_min[2][B=2][T=8]

#define NBLK_A 2048   // 4 vol x 16 z-blocks(8 z) x 32 y-chunks(4 y)
#define NBLK_B 256    // 4 vol x  4 z-blocks(16 z) x 16 y-chunks(4 y)
#define NBLK_TOTAL (NBLK_A + NBLK_B + 1)

__device__ __forceinline__ float fmax3(float a, float b, float c) {
    return fmaxf(a, fmaxf(b, c));
}

__device__ __forceinline__ float4 fmax3v(float4 a, float4 b, float4 c) {
    return make_float4(fmax3(a.x, b.x, c.x), fmax3(a.y, b.y, c.y),
                       fmax3(a.z, b.z, c.z), fmax3(a.w, b.w, c.w));
}

// One thread: fixed (x-quad, z), 4 output rows y0..y0+3. ALL 18 logit row-quads
// + 4 gt quads loaded into registers up-front (independent -> ~22-deep MLP),
// THEN folded. x-halo via wave shuffle (xq contiguous within a z-group);
// y/z boundary via index clamping (duplicate in-window value, max unchanged).
template <int D, int LOG2D, int XQ>
__device__ __forceinline__ void neg_march(
    const float* __restrict__ logits, const float* __restrict__ gt,
    int vol, int z, int y0, int xq, float& loss, float& wsum)
{
    const int x0 = xq << 2;
    const float* vb = logits + (vol << (3 * LOG2D));
    const int zm = z > 0 ? z - 1 : 0;
    const int zp = z < D - 1 ? z + 1 : z;
    const float* pzm = vb + (zm << (2 * LOG2D));
    const float* pz0 = vb + (z << (2 * LOG2D));
    const float* pzp = vb + (zp << (2 * LOG2D));
    const float* pg = gt + (vol << (3 * LOG2D)) + (z << (2 * LOG2D));

    float4 R[6][3];   // [row s][zplane] raw quads
    float4 G[4];      // gt quads for the 4 output rows
#pragma unroll
    for (int s = 0; s < 6; ++s) {
        int yy = y0 - 1 + s;
        yy = yy < 0 ? 0 : (yy > D - 1 ? D - 1 : yy);
        const int ro = (yy << LOG2D) + x0;
        R[s][0] = *(const float4*)(pzm + ro);
        R[s][1] = *(const float4*)(pz0 + ro);
        R[s][2] = *(const float4*)(pzp + ro);
    }
#pragma unroll
    for (int j = 0; j < 4; ++j)
        G[j] = *(const float4*)(pg + ((y0 + j) << LOG2D) + x0);

    float4 zf[6];     // per-row z-window column maxes
#pragma unroll
    for (int s = 0; s < 6; ++s) zf[s] = fmax3v(R[s][0], R[s][1], R[s][2]);

#pragma unroll
    for (int r = 0; r < 4; ++r) {
        float4 cz = fmax3v(zf[r], zf[r + 1], zf[r + 2]);   // y-fold
        float lco = __shfl_up(cz.w, 1);   if (xq == 0)      lco = cz.x;
        float rco = __shfl_down(cz.x, 1); if (xq == XQ - 1) rco = cz.w;
        float m0 = fmax3(lco, cz.x, cz.y);
        float m1 = fmax3(cz.x, cz.y, cz.z);
        float m2 = fmax3(cz.y, cz.z, cz.w);
        float m3 = fmax3(cz.z, cz.w, rco);
        float4 c = R[r + 1][1];           // center row, center plane
        float4 gq = G[r];
        float ms[4] = {m0, m1, m2, m3};
        float cs[4] = {c.x, c.y, c.z, c.w};
        float gs[4] = {gq.x, gq.y, gq.z, gq.w};
#pragma unroll
        for (int k = 0; k < 4; ++k) {
            if (gs[k] == -1.0f && ms[k] == cs[k]) {
                float e = __expf(cs[k]);                 // e^x
                float u = __builtin_amdgcn_rcpf(1.0f + e);
                float sc = e * u;                        // sigmoid(x)
                float wv = sc * sc;
                wsum += wv;
                loss += (-__logf(u)) * wv;               // softplus(x)
            }
        }
    }
}

__global__ __launch_bounds__(256, 4) void fused_kernel(
    const float* __restrict__ la, const float* __restrict__ lb,
    const float* __restrict__ ga, const float* __restrict__ gb,
    const int* __restrict__ conn_a, const int* __restrict__ conn_b,
    const int* __restrict__ coord_a, const int* __restrict__ coord_b,
    float* __restrict__ ws, float* __restrict__ out)
{
    __shared__ float sred[8];
    __shared__ float w1s[128];
    __shared__ float tgf[128];
    const int bid = blockIdx.x;
    const int t = threadIdx.x;
    float loss = 0.0f, wsum = 0.0f;
    int accIdx = -1;

    if (bid < NBLK_A) {
        // level a: D=128. xq = t&31 (32 quads), zs = t>>5 (8 z per block)
        accIdx = 0;
        const int vol = bid >> 9;
        const int rem = bid & 511;
        const int zb = rem >> 5, yc = rem & 31;
        neg_march<128, 7, 32>(la, ga, vol, zb * 8 + (t >> 5), yc * 4, t & 31,
                              loss, wsum);
    } else if (bid < NBLK_A + NBLK_B) {
        // level b: D=64. xq = t&15 (16 quads), zs = t>>4 (16 z per block)
        accIdx = 2;
        const int b2 = bid - NBLK_A;
        const int vol = b2 >> 6;
        const int rem = b2 & 63;
        const int zb = rem >> 4, yc = rem & 15;
        neg_march<64, 6, 16>(lb, gb, vol, zb * 16 + (t >> 4), yc * 4, t & 15,
                             loss, wsum);
    } else {
        // pos block: both levels, 128 active threads
        for (int level = 0; level < 2; ++level) {
            const float* logits = level ? lb : la;
            const int* conn = level ? conn_b : conn_a;
            const int* coord = level ? coord_b : coord_a;
            const int D = level ? 64 : 128;
            float li = 0.0f, ci = 0.0f;
            if (t < 128) {
                const int* c4 = coord + t * 4;
                int a = c4[0], zz = c4[1], yy = c4[2], xx = c4[3];
                bool valid = a > -1;
                int aa = valid ? a : 0, z2 = valid ? zz : 0,
                    y2 = valid ? yy : 0, x2 = valid ? xx : 0;
                int b = t >> 6;
                int off = (((b * 2 + aa) * D + z2) * D + y2) * D + x2;
                float lp = logits[off];
                int tag = conn[off];
                float s = 1.0f / (1.0f + expf(lp));   // 1 - sigmoid(lp)
                float w1 = s * s;
                float vf = valid ? 1.0f : 0.0f;
                float sp = fmaxf(-lp, 0.0f) + log1pf(expf(-fabsf(lp)));  // softplus(-lp)
                li = sp * w1 * vf;
                ci = w1 * vf;
                w1s[t] = w1;
                tgf[t] = (float)(valid ? tag : -1);
            }
            for (int o = 32; o; o >>= 1) {
                li += __shfl_down(li, o);
                ci += __shfl_down(ci, o);
            }
            if ((t & 63) == 0) { sred[t >> 6] = li; sred[4 + (t >> 6)] = ci; }
            __syncthreads();
            if (t == 0) {
                atomicAdd(ws + 4 + 2 * level, sred[0] + sred[1] + sred[2] + sred[3]);
                atomicAdd(ws + 5 + 2 * level, sred[4] + sred[5] + sred[6] + sred[7]);
            }
            if (t < 16) {
                int bb = t >> 3, tg = t & 7;
                float mn = INFINITY;
                for (int i = 0; i < 64; ++i) {
                    int j = bb * 64 + i;
                    if (tgf[j] == (float)tg) mn = fminf(mn, w1s[j]);
                }
                out[6 + level * 16 + bb * 8 + tg] = isinf(mn) ? -1.0f : mn;
            }
            __syncthreads();
        }
    }

    if (accIdx >= 0) {
        for (int o = 32; o; o >>= 1) {
            loss += __shfl_down(loss, o);
            wsum += __shfl_down(wsum, o);
        }
        if ((t & 63) == 0) { sred[t >> 6] = loss; sred[4 + (t >> 6)] = wsum; }
        __syncthreads();
        if (t == 0) {
            float L = sred[0] + sred[1] + sred[2] + sred[3];
            float W = sred[4] + sred[5] + sred[6] + sred[7];
            if (L != 0.0f || W != 0.0f) {
                atomicAdd(ws + accIdx, L);
                atomicAdd(ws + accIdx + 1, W);
            }
        }
    }

    // last-block finalize
    if (t == 0) {
        __threadfence();
        unsigned int old = atomicAdd((unsigned int*)(ws + 8), 1u);
        if (old == NBLK_TOTAL - 1) {
            float s0 = atomicAdd(ws + 0, 0.0f);
            float s1 = atomicAdd(ws + 1, 0.0f);
            float s2 = atomicAdd(ws + 2, 0.0f);
            float s3 = atomicAdd(ws + 3, 0.0f);
            float s4 = atomicAdd(ws + 4, 0.0f);
            float s5 = atomicAdd(ws + 5, 0.0f);
            float s6 = atomicAdd(ws + 6, 0.0f);
            float s7 = atomicAdd(ws + 7, 0.0f);
            out[0] = s4 * 2.0f + s6;   // cls_loss_pos (POS_FACTOR {2,1})
            out[1] = s0 * 2.0f + s2;   // cls_loss_neg (NEG_FACTOR {2,1})
            out[2] = s5 + s7;          // count_pos
            out[3] = s1 + s3;          // count_neg
            out[4] = s5 * 2.0f + s7;   // wsum_pos (anchor factor == 1)
            out[5] = s1 * 2.0f + s3;   // wsum_neg
        }
    }
}

extern "C" void kernel_launch(void* const* d_in, const int* in_sizes, int n_in,
                              void* d_out, int out_size, void* d_ws, size_t ws_size,
                              hipStream_t stream) {
    const float* logits_a = (const float*)d_in[0];
    const float* logits_b = (const float*)d_in[1];
    const float* prob_a   = (const float*)d_in[2];
    const float* prob_b   = (const float*)d_in[3];
    const int*   conn_a   = (const int*)d_in[4];
    const int*   conn_b   = (const int*)d_in[5];
    const int*   coord_a  = (const int*)d_in[6];
    const int*   coord_b  = (const int*)d_in[7];
    float* out = (float*)d_out;
    float* ws  = (float*)d_ws;

    hipMemsetAsync(ws, 0, 12 * sizeof(float), stream);
    fused_kernel<<<NBLK_TOTAL, 256, 0, stream>>>(
        logits_a, logits_b, prob_a, prob_b,
        conn_a, conn_b, coord_a, coord_b, ws, out);
}